// Round 9
// baseline (881.051 us; speedup 1.0000x reference)
//
#include <hip/hip_runtime.h>

// QuantumDenseNet R21: R20's observable fold with the scratch-spill fixed.
// R20 post-mortem: meas_fiber's ra[6]/ma[6]/... arrays were runtime-indexed
// (pair loop didn't fully unroll) -> allocated in SCRATCH -> 1.2 GB/dispatch
// of private-memory traffic (FETCH 549MB, WRITE 653MB), qnet 636->790us.
// Fix: meas_fiber rewritten with NAMED SCALARS and the 15 Hermitian pair
// terms macro-expanded with compile-time W[] offsets. No private arrays.
// Fold math unchanged (verified: absmax identical): X~ = G† X G replaces the
// final Dp passes on modes 0,1; final half-layer = 8 BS passes, zero SG.

typedef float    vf2 __attribute__((ext_vector_type(2)));
typedef _Float16 h2  __attribute__((ext_vector_type(2)));
typedef _Float16 h4  __attribute__((ext_vector_type(4)));

__device__ __forceinline__ h2 pkfma(const h2 a, const h2 b, const h2 c) {
    return __builtin_elementwise_fma(a, b, c);
}

__device__ __forceinline__ void cmadd(float &ax, float &ay, const float2 u, const float2 v) {
    ax = fmaf(u.x, v.x, ax);
    ax = fmaf(-u.y, v.y, ax);
    ay = fmaf(u.x, v.y, ay);
    ay = fmaf(u.y, v.x, ay);
}

// block-diagonal structure of the 36x36 BS gate (total photon number n=0..10)
constexpr int BS_SN[11]  = {1,2,3,4,5,6,5,4,3,2,1};
constexpr int BS_OFF[11] = {0,1,5,14,30,55,91,116,132,141,145};
// mode strides (amp units): {6, 1, 36, 221, 1334}; max addr 7990

// runtime-indexed copy for prep_kernel packing + in-kernel head peel
__device__ const int d_BS_OFF[12] = {0,1,5,14,30,55,91,116,132,141,145,146};
__device__ const int d_BS_SN[11]  = {1,2,3,4,5,6,5,4,3,2,1};

// ---------------------------------------------------------------------------
// Fused prep kernel (identical to R20):
//   blocks 0..79  -> BS gates (order-10 Taylor, s=2) broadcast-packed
//   block  80     -> 40 single-mode gates (order-10, s=2) + X~ for final Dp
//   blocks 81+    -> dcol column 0 via vector Horner (order 30)
// ---------------------------------------------------------------------------
__global__ void prep_kernel(const float* __restrict__ lin,
                            const float* __restrict__ act,
                            const float* __restrict__ lact,
                            const float* __restrict__ x,
                            h2* __restrict__ bsh,
                            h2* __restrict__ sgh,
                            float* __restrict__ xobs,
                            float* __restrict__ dcol,
                            const int total)
{
    __shared__ float2 B0[1296];
    __shared__ float2 B1[1296];
    const int tid = threadIdx.x;

    if (blockIdx.x < 80) {
        const int g = blockIdx.x;
        const int l = g / 20;
        const int w = g % 20;
        const int q = w / 10;
        const int n = w % 10;
        const float theta = lin[l*63 + (q ? 29 : 0) + n];
        const float phi   = lin[l*63 + (q ? 39 : 10) + n];
        const float ts = theta * 0.25f;                 // s=2 scaling
        const float cp = cosf(phi), sp = sinf(phi);
        const float2 u  = make_float2( ts*cp, ts*sp);
        const float2 w2 = make_float2(-ts*cp, ts*sp);

        float2 *R = B0, *T = B1;
        for (int e = tid; e < 1296; e += 256)
            R[e] = make_float2((e % 37 == 0) ? 1.f : 0.f, 0.f);
        __syncthreads();

        for (int k = 10; k >= 1; --k) {
            const float invk = 1.f / (float)k;
            for (int e = tid; e < 1296; e += 256) {
                const int row = e / 36, c = e - row*36;
                const int i = row / 6, j = row - (row/6)*6;
                float ax = 0.f, ay = 0.f;
                if (i < 5 && j > 0) {
                    const float coef = sqrtf((float)((i+1)*j));
                    const float2 xv = R[(row+5)*36 + c];
                    const float px = u.x*xv.x - u.y*xv.y;
                    const float py = u.x*xv.y + u.y*xv.x;
                    ax = fmaf(coef, px, ax); ay = fmaf(coef, py, ay);
                }
                if (i > 0 && j < 5) {
                    const float coef = sqrtf((float)(i*(j+1)));
                    const float2 xv = R[(row-5)*36 + c];
                    const float px = w2.x*xv.x - w2.y*xv.y;
                    const float py = w2.x*xv.y + w2.y*xv.x;
                    ax = fmaf(coef, px, ax); ay = fmaf(coef, py, ay);
                }
                T[e] = make_float2(((row == c) ? 1.f : 0.f) + ax*invk, ay*invk);
            }
            __syncthreads();
            float2* tmp = R; R = T; T = tmp;
        }
        for (int s2 = 0; s2 < 2; ++s2) {                // s=2 squarings
            for (int e = tid; e < 1296; e += 256) {
                const int row = e / 36, c = e - row*36;
                float ax = 0.f, ay = 0.f;
                #pragma unroll 6
                for (int k = 0; k < 36; ++k)
                    cmadd(ax, ay, R[row*36 + k], R[k*36 + c]);
                T[e] = make_float2(ax, ay);
            }
            __syncthreads();
            float2* tmp = R; R = T; T = tmp;
        }
        for (int idx = tid; idx < 146; idx += 256) {
            int nn = 0;
            while (idx >= d_BS_OFF[nn+1]) ++nn;
            const int sn  = d_BS_SN[nn];
            const int rel = idx - d_BS_OFF[nn];
            const int p = rel / sn, qq = rel % sn;
            const int imin = (nn > 5) ? (nn - 5) : 0;
            const int row = 5*(imin + p)  + nn;
            const int col = 5*(imin + qq) + nn;
            const float2 z = R[row*36 + col];
            bsh[g*292 + 2*idx    ] = (h2){(_Float16)z.x, (_Float16)z.x};
            bsh[g*292 + 2*idx + 1] = (h2){(_Float16)z.y, (_Float16)z.y};
        }
    } else if (blockIdx.x == 80) {
        const int t = tid;
        if (t >= 40) return;
        const int l  = t / 10;
        const int gi = t % 10;
        float2 G[36];
        if (gi < 5) {
            // Sq[m] = squeeze(r) @ diag(e^{i rphi1 * n})  (parity-banded)
            const int m = gi;
            const float r    = lin[l*63 + 24 + m];
            const float rphi = (m < 4) ? lin[l*63 + 20 + m] : 0.f;
            float R[36], T[36];
            #pragma unroll
            for (int e = 0; e < 36; ++e) R[e] = (e % 7 == 0) ? 1.f : 0.f;
            float hp[4];
            #pragma unroll
            for (int i = 0; i < 4; ++i)
                hp[i] = 0.5f * r * sqrtf((float)((i+1)*(i+2))) * 0.25f;
            for (int k = 10; k >= 1; --k) {
                const float invk = 1.f / (float)k;
                #pragma unroll
                for (int i = 0; i < 6; ++i) {
                    #pragma unroll
                    for (int c = 0; c < 6; ++c) {
                        float a = 0.f;
                        if (i < 4)  a = fmaf( hp[i],   R[(i+2)*6 + c], a);
                        if (i >= 2) a = fmaf(-hp[i-2], R[(i-2)*6 + c], a);
                        T[i*6+c] = ((i == c) ? 1.f : 0.f) + a*invk;
                    }
                }
                #pragma unroll
                for (int e = 0; e < 36; ++e) R[e] = T[e];
            }
            for (int s2 = 0; s2 < 2; ++s2) {
                #pragma unroll
                for (int i = 0; i < 6; ++i) {
                    #pragma unroll
                    for (int c = 0; c < 6; ++c) {
                        float a = 0.f;
                        #pragma unroll
                        for (int k = 0; k < 6; ++k) a = fmaf(R[i*6+k], R[k*6+c], a);
                        T[i*6+c] = a;
                    }
                }
                #pragma unroll
                for (int e = 0; e < 36; ++e) R[e] = T[e];
            }
            #pragma unroll
            for (int c = 0; c < 6; ++c) {
                const float cc = cosf(rphi * (float)c), ss = sinf(rphi * (float)c);
                #pragma unroll
                for (int o = 0; o < 6; ++o)
                    G[o*6 + c] = make_float2(R[o*6+c]*cc, R[o*6+c]*ss);
            }
        } else {
            // Dp[m] = diag(e^{i kap n^2}) @ disp(dr,dp) @ diag(e^{i rphi2 n})
            const int m = gi - 5;
            const float dr   = lin[l*63 + 53 + m];
            const float dp   = lin[l*63 + 58 + m];
            const float rphi = (m < 4) ? lin[l*63 + 49 + m] : 0.f;
            const float kap  = (l < 3) ? act[l*5 + m] : ((m < 2) ? lact[m] : 0.f);
            const float2 al = make_float2(dr * cosf(dp), dr * sinf(dp));
            float2 R[36], T[36];
            #pragma unroll
            for (int e = 0; e < 36; ++e)
                R[e] = make_float2((e % 7 == 0) ? 1.f : 0.f, 0.f);
            float2 cm[6], cpb[6];
            #pragma unroll
            for (int i = 0; i < 6; ++i) {
                const float sm  = sqrtf((float)i)     * 0.25f;
                const float sp2 = sqrtf((float)(i+1)) * 0.25f;
                cm[i]  = make_float2( al.x*sm,  al.y*sm);
                cpb[i] = make_float2(-al.x*sp2, al.y*sp2);
            }
            for (int k = 10; k >= 1; --k) {
                const float invk = 1.f / (float)k;
                #pragma unroll
                for (int i = 0; i < 6; ++i) {
                    #pragma unroll
                    for (int c = 0; c < 6; ++c) {
                        float ax = 0.f, ay = 0.f;
                        if (i >= 1) cmadd(ax, ay, cm[i],  R[(i-1)*6 + c]);
                        if (i < 5)  cmadd(ax, ay, cpb[i], R[(i+1)*6 + c]);
                        T[i*6+c] = make_float2(((i == c) ? 1.f : 0.f) + ax*invk, ay*invk);
                    }
                }
                #pragma unroll
                for (int e = 0; e < 36; ++e) R[e] = T[e];
            }
            for (int s2 = 0; s2 < 2; ++s2) {
                #pragma unroll
                for (int i = 0; i < 6; ++i) {
                    #pragma unroll
                    for (int c = 0; c < 6; ++c) {
                        float ax = 0.f, ay = 0.f;
                        #pragma unroll
                        for (int k = 0; k < 6; ++k) cmadd(ax, ay, R[i*6+k], R[k*6+c]);
                        T[i*6+c] = make_float2(ax, ay);
                    }
                }
                #pragma unroll
                for (int e = 0; e < 36; ++e) R[e] = T[e];
            }
            #pragma unroll
            for (int o = 0; o < 6; ++o) {
                const float ko = kap * (float)(o*o);
                const float2 kp = make_float2(cosf(ko), sinf(ko));
                #pragma unroll
                for (int c = 0; c < 6; ++c) {
                    const float rc = rphi * (float)c;
                    const float2 rp = make_float2(cosf(rc), sinf(rc));
                    const float2 z = R[o*6 + c];
                    const float2 t1 = make_float2(kp.x*z.x - kp.y*z.y, kp.x*z.y + kp.y*z.x);
                    G[o*6 + c] = make_float2(t1.x*rp.x - t1.y*rp.y, t1.x*rp.y + t1.y*rp.x);
                }
            }
            // X~ = G† X G for the final layer's Dp on measured modes 0,1 (f32)
            if (l == 3 && m < 2) {
                float2 XG[36];
                #pragma unroll
                for (int o = 0; o < 6; ++o) {
                    #pragma unroll
                    for (int c = 0; c < 6; ++c) {
                        float xr = 0.f, xi = 0.f;
                        if (o >= 1) {
                            const float s_ = sqrtf((float)o);
                            xr = fmaf(s_, G[(o-1)*6+c].x, xr);
                            xi = fmaf(s_, G[(o-1)*6+c].y, xi);
                        }
                        if (o < 5) {
                            const float s_ = sqrtf((float)(o+1));
                            xr = fmaf(s_, G[(o+1)*6+c].x, xr);
                            xi = fmaf(s_, G[(o+1)*6+c].y, xi);
                        }
                        XG[o*6+c] = make_float2(xr, xi);
                    }
                }
                float* xo_ = xobs + m*36;
                #pragma unroll
                for (int i = 0; i < 6; ++i) {
                    float d = 0.f;
                    #pragma unroll
                    for (int o = 0; o < 6; ++o)
                        d += G[o*6+i].x*XG[o*6+i].x + G[o*6+i].y*XG[o*6+i].y;
                    xo_[i] = 0.5f * d;
                }
                int pk = 6;
                for (int i = 0; i < 6; ++i) {
                    for (int j = i+1; j < 6; ++j) {
                        float er = 0.f, ei = 0.f;
                        #pragma unroll
                        for (int o = 0; o < 6; ++o) {
                            const float2 gv = G[o*6+i], xg = XG[o*6+j];
                            er = fmaf(gv.x, xg.x, er); er = fmaf(gv.y, xg.y, er);
                            ei = fmaf(gv.x, xg.y, ei); ei = fmaf(-gv.y, xg.x, ei);
                        }
                        xo_[pk] = er; xo_[pk+1] = ei; pk += 2;
                    }
                }
            }
        }
        h2* outp = sgh + (l*10 + gi)*72;
        #pragma unroll
        for (int e = 0; e < 36; ++e) {
            outp[2*e    ] = (h2){(_Float16)G[e].x, (_Float16)G[e].x};
            outp[2*e + 1] = (h2){(_Float16)G[e].y, (_Float16)G[e].y};
        }
    } else {
        // dcol: column 0 of expm(x(A†-A)) via vector Horner, order 30, s=0.
        const int i = (blockIdx.x - 81) * 256 + tid;
        if (i >= total) return;
        const float xv = x[i];
        float a[5];
        #pragma unroll
        for (int j = 0; j < 5; ++j) a[j] = xv * sqrtf((float)(j+1));
        float w[6];
        #pragma unroll
        for (int j = 0; j < 6; ++j) w[j] = (j == 0) ? 1.f : 0.f;
        for (int k = 30; k >= 1; --k) {
            const float invk = 1.f / (float)k;
            float t[6];
            #pragma unroll
            for (int r = 0; r < 6; ++r) {
                float acc = 0.f;
                if (r >= 1) acc = fmaf( a[r-1], w[r-1], acc);
                if (r < 5)  acc = fmaf(-a[r],   w[r+1], acc);
                t[r] = ((r == 0) ? 1.f : 0.f) + acc*invk;
            }
            #pragma unroll
            for (int j = 0; j < 6; ++j) w[j] = t[j];
        }
        #pragma unroll
        for (int j = 0; j < 6; ++j) dcol[i*6 + j] = w[j];
    }
}

// ---------------------------------------------------------------------------
// Main kernel building blocks (batch-pair packed, 8B complex amplitudes)
// ---------------------------------------------------------------------------

template<int SA, int SB, int n, int R0, int R1>
__device__ __forceinline__ void bs_rows(const h2* __restrict__ U,
                                        h4* __restrict__ psi,
                                        const int base, const bool act)
{
    constexpr int sn = BS_SN[n], uoff = BS_OFF[n];
    constexpr int imin = (n > 5) ? (n - 5) : 0;
    if (!act) return;
    h2 vR[sn], vI[sn];
    #pragma unroll
    for (int q = 0; q < sn; ++q) {
        const int c = 5*(imin + q) + n;
        const h4 v = psi[base + (c/6)*SA + (c%6)*SB];
        vR[q] = (h2){v.x, v.y};
        vI[q] = (h2){v.z, v.w};
    }
    h2 oR[R1-R0], oI[R1-R0];
    #pragma unroll
    for (int p = R0; p < R1; ++p) {
        const h2* Up = U + 2*(uoff + p*sn);
        h2 ur = Up[0], ui = Up[1];
        h2 aR = ur * vR[0];
        aR = pkfma(-ui, vI[0], aR);
        h2 aI = ur * vI[0];
        aI = pkfma(ui, vR[0], aI);
        #pragma unroll
        for (int q = 1; q < sn; ++q) {
            ur = Up[2*q]; ui = Up[2*q + 1];
            aR = pkfma(ur, vR[q], aR);
            aR = pkfma(-ui, vI[q], aR);
            aI = pkfma(ur, vI[q], aI);
            aI = pkfma(ui, vR[q], aI);
        }
        oR[p-R0] = aR; oI[p-R0] = aI;
    }
    #pragma unroll
    for (int p = R0; p < R1; ++p) {
        const int c = 5*(imin + p) + n;
        const h2 r = oR[p-R0], m = oI[p-R0];
        psi[base + (c/6)*SA + (c%6)*SB] = (h4){r.x, r.y, m.x, m.y};
    }
}

// BS pass: 4 wave-aligned quarters of 256 threads; whole-block groups.
// packed-cMAC: q0={5}=36, q1={4,2,1}=38, q2={6,8,9}=38, q3={3,7,0,10}=34.
template<int SA, int SB>
__device__ __forceinline__ void pass_bs(const h2* __restrict__ U,
                                        h4* __restrict__ psi,
                                        const int base, const bool act, const int qid)
{
    if (qid == 0) {
        bs_rows<SA,SB,5,0,6>(U, psi, base, act);
    } else if (qid == 1) {
        bs_rows<SA,SB,4,0,5>(U, psi, base, act);
        bs_rows<SA,SB,2,0,3>(U, psi, base, act);
        bs_rows<SA,SB,1,0,2>(U, psi, base, act);
    } else if (qid == 2) {
        bs_rows<SA,SB,6,0,5>(U, psi, base, act);
        bs_rows<SA,SB,8,0,3>(U, psi, base, act);
        bs_rows<SA,SB,9,0,2>(U, psi, base, act);
    } else {
        bs_rows<SA,SB,3,0,4>(U, psi, base, act);
        bs_rows<SA,SB,7,0,4>(U, psi, base, act);
        bs_rows<SA,SB,0,0,1>(U, psi, base, act);
        bs_rows<SA,SB,10,0,1>(U, psi, base, act);
    }
    __syncthreads();
}

// one single-mode-gate fiber (6 amplitudes, stride SM), 8B-packed
template<int SM, bool SP>
__device__ __forceinline__ void sg_fiber(const h2* __restrict__ G,
                                         h4* __restrict__ psi,
                                         const int base)
{
    h2 vR[6], vI[6];
    #pragma unroll
    for (int k = 0; k < 6; ++k) {
        const h4 v = psi[base + k*SM];
        vR[k] = (h2){v.x, v.y};
        vI[k] = (h2){v.z, v.w};
    }
    h2 oR[6], oI[6];
    #pragma unroll
    for (int o = 0; o < 6; ++o) {
        const int k0 = SP ? (o & 1) : 0;
        const int st = SP ? 2 : 1;
        h2 ur = G[2*(o*6 + k0)], ui = G[2*(o*6 + k0) + 1];
        h2 aR = ur * vR[k0];
        aR = pkfma(-ui, vI[k0], aR);
        h2 aI = ur * vI[k0];
        aI = pkfma(ui, vR[k0], aI);
        #pragma unroll
        for (int k = k0 + st; k < 6; k += st) {
            ur = G[2*(o*6 + k)]; ui = G[2*(o*6 + k) + 1];
            aR = pkfma(ur, vR[k], aR);
            aR = pkfma(-ui, vI[k], aR);
            aI = pkfma(ur, vI[k], aI);
            aI = pkfma(ui, vR[k], aI);
        }
        oR[o] = aR; oI[o] = aI;
    }
    #pragma unroll
    for (int o = 0; o < 6; ++o)
        psi[base + o*SM] = (h4){oR[o].x, oR[o].y, oI[o].x, oI[o].y};
}

// single-mode gate pass: 1296 fibers over 1024 threads (ragged second round).
template<int SM, int S0, int S1, int S2, int S3, bool SP>
__device__ __forceinline__ void pass_sg(const h2* __restrict__ G,
                                        h4* __restrict__ psi,
                                        const int4 dg0, const int4 dg1, const bool act1)
{
    {
        const int base = dg0.x*S0 + dg0.y*S1 + dg0.z*S2 + dg0.w*S3;
        sg_fiber<SM,SP>(G, psi, base);
    }
    if (act1) {
        const int base = dg1.x*S0 + dg1.y*S1 + dg1.z*S2 + dg1.w*S3;
        sg_fiber<SM,SP>(G, psi, base);
    }
    __syncthreads();
}

// dense Hermitian quadratic form v† X~ v for one fiber (6 amps), both batches.
// FULLY SCALARIZED (no private arrays -> no scratch; rule-#20 fix for R20).
// W layout: W[0..5] = 0.5*Re X~_ii; then 15 (i<j) pairs as (Re,Im) at 6+2p.
#define MLOAD(k) \
    const h4 v##k = psi[base + stride*k]; \
    const float ra##k = (float)v##k.x, rb##k = (float)v##k.y; \
    const float ma##k = (float)v##k.z, mb##k = (float)v##k.w;
#define MDIAG(k) \
    sa = fmaf(W[k], fmaf(ra##k, ra##k, ma##k*ma##k), sa); \
    sb = fmaf(W[k], fmaf(rb##k, rb##k, mb##k*mb##k), sb);
#define MPAIR(i, j, off) { \
    const float Xr = W[off], Xi = W[(off)+1]; \
    sa = fmaf(Xr, fmaf(ra##i, ra##j, ma##i*ma##j), sa); \
    sa = fmaf(-Xi, fmaf(ra##i, ma##j, -(ma##i*ra##j)), sa); \
    sb = fmaf(Xr, fmaf(rb##i, rb##j, mb##i*mb##j), sb); \
    sb = fmaf(-Xi, fmaf(rb##i, mb##j, -(mb##i*rb##j)), sb); }

__device__ __forceinline__ void meas_fiber(const h4* __restrict__ psi,
                                           const int base, const int stride,
                                           const float* __restrict__ W,
                                           float &sa, float &sb)
{
    MLOAD(0) MLOAD(1) MLOAD(2) MLOAD(3) MLOAD(4) MLOAD(5)
    MDIAG(0) MDIAG(1) MDIAG(2) MDIAG(3) MDIAG(4) MDIAG(5)
    MPAIR(0,1, 6)  MPAIR(0,2, 8)  MPAIR(0,3,10) MPAIR(0,4,12) MPAIR(0,5,14)
    MPAIR(1,2,16)  MPAIR(1,3,18)  MPAIR(1,4,20) MPAIR(1,5,22)
    MPAIR(2,3,24)  MPAIR(2,4,26)  MPAIR(2,5,28)
    MPAIR(3,4,30)  MPAIR(3,5,32)
    MPAIR(4,5,34)
}

__global__ __launch_bounds__(1024, 8)
void qnet_kernel(const h2* __restrict__ bs,
                 const h2* __restrict__ sg,
                 const float* __restrict__ xobs,
                 const float* __restrict__ dcol,
                 float* __restrict__ out,
                 const int B)
{
    // addr = 6*i0 + i1 + 36*i2 + 221*i3 + 1334*i4 (max 7990), 8B per amplitude
    __shared__ __align__(16) h4 psi[7992];      // 63,936 B
    __shared__ float stf[60];
    __shared__ float red[64];
    __shared__ float xo[72];
    // head-peel staging (f32): psi01/psi23 per batch (36), f234 per batch (216)
    __shared__ float2 ps01[2][36];
    __shared__ float2 ps23[2][36];
    __shared__ float2 f234[2][216];

    const int tid = threadIdx.x;
    const int b   = blockIdx.x;          // batch pair (2b, 2b+1)

    const int lim = B * 30;
    if (tid < 60) stf[tid] = (b*60 + tid < lim) ? dcol[b*60 + tid] : 0.f;
    else if (tid >= 64 && tid < 136) xo[tid - 64] = xobs[tid - 64];
    __syncthreads();

    // ---- head peel round A: psi01 = BS01@(d0⊗d1), psi23 = BS23@(d2⊗d3) ----
    if (tid < 144) {
        const int part = tid / 36;       // 0:ps01 b0, 1:ps01 b1, 2:ps23 b0, 3:ps23 b1
        const int idx  = tid - part*36;
        const int p    = part & 1;
        const bool m01 = part < 2;
        const int i = idx / 6, j = idx - (idx/6)*6;
        const int n = i + j;
        const int imin = (n > 5) ? (n - 5) : 0;
        const int sn   = d_BS_SN[n];
        const int prow = i - imin;
        const h2* U = bs + (m01 ? 0 : 1)*292 + 2*(d_BS_OFF[n] + prow*sn);
        const float* dA = stf + p*30 + (m01 ? 0 : 12);
        const float* dB = dA + 6;
        float ar = 0.f, ai = 0.f;
        for (int q = 0; q < sn; ++q) {
            const float ur = (float)U[2*q].x, ui = (float)U[2*q+1].x;
            const float dd = dA[imin+q] * dB[n-imin-q];
            ar = fmaf(ur, dd, ar); ai = fmaf(ui, dd, ai);
        }
        if (m01) ps01[p][idx] = make_float2(ar, ai);
        else     ps23[p][idx] = make_float2(ar, ai);
    }
    __syncthreads();

    // ---- head peel round B: f234 = BS34@(psi23⊗d4) ----
    if (tid < 432) {
        const int p  = tid / 216;
        const int r  = tid - p*216;
        const int i2 = r / 36, i34 = r - i2*36;
        const int i3 = i34 / 6, i4 = i34 - i3*6;
        const int n  = i3 + i4;
        const int imin = (n > 5) ? (n - 5) : 0;
        const int sn   = d_BS_SN[n];
        const int prow = i3 - imin;
        const h2* U = bs + 3*292 + 2*(d_BS_OFF[n] + prow*sn);
        const float* d4 = stf + p*30 + 24;
        float ar = 0.f, ai = 0.f;
        for (int q = 0; q < sn; ++q) {
            const float ur = (float)U[2*q].x, ui = (float)U[2*q+1].x;
            const float2 w23 = ps23[p][i2*6 + (imin+q)];
            const float dd = d4[n-imin-q];
            ar = fmaf(dd, ur*w23.x - ui*w23.y, ar);
            ai = fmaf(dd, ur*w23.y + ui*w23.x, ai);
        }
        f234[p][r] = make_float2(ar, ai);
    }
    __syncthreads();

    // ---- init: psi = psi01 ⊗ f234 (complex product, rounded once to f16) ----
    for (int e = tid; e < 7776; e += 1024) {
        int t = e;
        const int i4 = t % 6; t /= 6;
        const int i3 = t % 6; t /= 6;
        const int i2 = t % 6; t /= 6;
        const int i1 = t % 6; t /= 6;
        const int i0 = t;
        const int addr = 6*i0 + i1 + 36*i2 + 221*i3 + 1334*i4;
        const int i01 = i0*6 + i1;
        const int r   = i2*36 + i3*6 + i4;
        const float2 a0 = ps01[0][i01], b0 = f234[0][r];
        const float2 a1 = ps01[1][i01], b1 = f234[1][r];
        const float v0r = a0.x*b0.x - a0.y*b0.y, v0i = a0.x*b0.y + a0.y*b0.x;
        const float v1r = a1.x*b1.x - a1.y*b1.y, v1i = a1.x*b1.y + a1.y*b1.x;
        psi[addr] = (h4){(_Float16)v0r, (_Float16)v1r, (_Float16)v0i, (_Float16)v1i};
    }
    __syncthreads();

    // BS mapping: 4 quarters of 256; sub<216 active; fiber f = sub
    const int sub = tid & 255;
    const int qid = __builtin_amdgcn_readfirstlane(tid >> 8);   // wave-uniform
    const bool act = sub < 216;
    const int f = act ? sub : 215;
    const int fa = f / 36, rem = f - fa*36;
    const int fb = rem / 6, fc = rem - fb*6;
    const int baseK0 = fa*36 + fb*221 + fc*1334;   // pair (0,1): spect 2,3,4
    const int baseK1 = fa*6  + fb*221 + fc*1334;   // pair (1,2): spect 0,3,4
    const int baseK2 = rem   + fa*1334;            // pair (2,3): spect 0,1 (contig), 4
    const int baseK3 = f;                          // pair (3,4): spect 0,1,2 (contig)

    // SG mapping: fibers tid and tid+1024 (<1296); digits precomputed once
    int4 dg0, dg1;
    { int t = tid;        dg0.x = t % 6; t /= 6; dg0.y = t % 6; t /= 6; dg0.z = t % 6; dg0.w = t / 6; }
    { int t = tid + 1024; dg1.x = t % 6; t /= 6; dg1.y = t % 6; t /= 6; dg1.z = t % 6; dg1.w = t / 6; }
    const bool act1 = tid < 272;

    for (int l = 0; l < 4; ++l) {
        const h2* bsl = bs + l * 20 * 292;
        const h2* sgl = sg + l * 10 * 72;
        for (int hf = 0; hf < 2; ++hf) {
            const h2* bh = bsl + hf * 10 * 292;
            const h2* sh = sgl + hf * 5 * 72;
            // head peel: first half-layer passes 0,1,3 already applied in init
            const bool first = (l == 0) && (hf == 0);
            // tail: final half-layer gates on modes {2,3,4} commute with the
            // measurement; Dp on modes {0,1} folded into X~ (observable fold).
            const bool last = (l == 3) && (hf == 1);
            // rail order k = {0,2,1,3,0,2,1,3,0,2}
            if (!first) {
                pass_bs<6,1>     (bh + 0*292, psi, baseK0, act, qid);
                pass_bs<36,221>  (bh + 1*292, psi, baseK2, act, qid);
            }
            pass_bs<1,36>    (bh + 2*292, psi, baseK1, act, qid);
            if (!first)
                pass_bs<221,1334>(bh + 3*292, psi, baseK3, act, qid);
            pass_bs<6,1>     (bh + 4*292, psi, baseK0, act, qid);
            pass_bs<36,221>  (bh + 5*292, psi, baseK2, act, qid);
            pass_bs<1,36>    (bh + 6*292, psi, baseK1, act, qid);
            if (!last)
                pass_bs<221,1334>(bh + 7*292, psi, baseK3, act, qid);
            pass_bs<6,1>     (bh + 8*292, psi, baseK0, act, qid);
            if (!last)
                pass_bs<36,221>  (bh + 9*292, psi, baseK2, act, qid);
            if (hf == 0) {   // squeeze gates: parity-sparse
                pass_sg<6,    1,36,221,1334, true>(sh + 0*72, psi, dg0, dg1, act1);
                pass_sg<1,    6,36,221,1334, true>(sh + 1*72, psi, dg0, dg1, act1);
                pass_sg<36,   1,6,221,1334,  true>(sh + 2*72, psi, dg0, dg1, act1);
                pass_sg<221,  1,6,36,1334,   true>(sh + 3*72, psi, dg0, dg1, act1);
                pass_sg<1334, 1,6,36,221,    true>(sh + 4*72, psi, dg0, dg1, act1);
            } else if (!last) {  // displacement gates: dense (last fully folded)
                pass_sg<6,    1,36,221,1334, false>(sh + 0*72, psi, dg0, dg1, act1);
                pass_sg<1,    6,36,221,1334, false>(sh + 1*72, psi, dg0, dg1, act1);
                pass_sg<36,   1,6,221,1334,  false>(sh + 2*72, psi, dg0, dg1, act1);
                pass_sg<221,  1,6,36,1334,   false>(sh + 3*72, psi, dg0, dg1, act1);
                pass_sg<1334, 1,6,36,221,    false>(sh + 4*72, psi, dg0, dg1, act1);
            }
        }
    }

    // <psi| X~_m |psi> on modes 0 (stride 6) and 1 (stride 1), dense Hermitian
    float s0a = 0.f, s0b = 0.f, s1a = 0.f, s1b = 0.f;
    for (int fr = tid; fr < 1296; fr += 1024) {
        const int q0 = fr % 6;
        const int q1 = (fr / 6) % 6;
        const int q2 = (fr / 36) % 6;
        const int q3 = fr / 216;
        const int base0 = q0*1 + q1*36 + q2*221 + q3*1334;   // spectators of mode 0
        meas_fiber(psi, base0, 6, xo,      s0a, s0b);
        const int base1 = q0*6 + q1*36 + q2*221 + q3*1334;   // spectators of mode 1
        meas_fiber(psi, base1, 1, xo + 36, s1a, s1b);
    }
    #pragma unroll
    for (int off = 32; off > 0; off >>= 1) {
        s0a += __shfl_down(s0a, off, 64);
        s0b += __shfl_down(s0b, off, 64);
        s1a += __shfl_down(s1a, off, 64);
        s1b += __shfl_down(s1b, off, 64);
    }
    if ((tid & 63) == 0) {
        const int w = tid >> 6;
        red[w*4 + 0] = s0a; red[w*4 + 1] = s1a;
        red[w*4 + 2] = s0b; red[w*4 + 3] = s1b;
    }
    __syncthreads();
    if (tid == 0) {
        float r0 = 0.f, r1 = 0.f, r2 = 0.f, r3 = 0.f;
        #pragma unroll
        for (int w = 0; w < 16; ++w) {
            r0 += red[w*4 + 0]; r1 += red[w*4 + 1];
            r2 += red[w*4 + 2]; r3 += red[w*4 + 3];
        }
        const int b0 = 2*b, b1 = 2*b + 1;
        out[b0*2 + 0] = 2.f * r0;
        out[b0*2 + 1] = 2.f * r1;
        if (b1 < B) {
            out[b1*2 + 0] = 2.f * r2;
            out[b1*2 + 1] = 2.f * r3;
        }
    }
}

// ---------------------------------------------------------------------------
extern "C" void kernel_launch(void* const* d_in, const int* in_sizes, int n_in,
                              void* d_out, int out_size, void* d_ws, size_t ws_size,
                              hipStream_t stream)
{
    const float* x    = (const float*)d_in[0];   // (B, 5)
    const float* lin  = (const float*)d_in[1];   // (4, 63)
    const float* act  = (const float*)d_in[2];   // (3, 5)
    const float* lact = (const float*)d_in[3];   // (5,)
    float* out = (float*)d_out;                  // (B, 2) float32

    const int B = in_sizes[0] / 5;

    // ws layout: 80 BS gates (292 h2) | 40 single gates (72 h2) | xobs (72 f32)
    //            | dcol f32
    h2*    bsh  = (h2*)d_ws;
    h2*    sgh  = bsh + 80*292;
    float* xobs = (float*)(sgh + 40*72);
    float* dc   = xobs + 72;

    const int total  = B * 5;
    const int nprep  = 81 + (total + 255) / 256;
    prep_kernel<<<dim3(nprep), dim3(256), 0, stream>>>(lin, act, lact, x, bsh, sgh, xobs, dc, total);
    qnet_kernel<<<dim3((B + 1) / 2), dim3(1024), 0, stream>>>(bsh, sgh, xobs, dc, out, B);
}

// Round 10
// 711.088 us; speedup vs baseline: 1.2390x; 1.2390x over previous
//
#include <hip/hip_runtime.h>

// QuantumDenseNet R22 = R19 byte-exact revert (best verified: bench 713us,
// qnet 636us). R20/R21 post-mortem: the observable fold triggered 1.2 GB of
// unexplained scratch-like traffic (WRITE 653MB with only 16KB of legitimate
// global stores) in BOTH the looped and fully-scalarized forms -- mechanism
// unidentified, upside only ~13us -> abandoned per post-mortem discipline.
// R19 state: batch-pair h4 packing, head peel (first 3 BS passes collapsed
// to f32 matvecs on the product state), tail commute-skip, fused fast prep
// (order-10+s=2 gates, vector-Horner dcol).

typedef float    vf2 __attribute__((ext_vector_type(2)));
typedef _Float16 h2  __attribute__((ext_vector_type(2)));
typedef _Float16 h4  __attribute__((ext_vector_type(4)));

__device__ __forceinline__ h2 pkfma(const h2 a, const h2 b, const h2 c) {
    return __builtin_elementwise_fma(a, b, c);
}

__device__ __forceinline__ void cmadd(float &ax, float &ay, const float2 u, const float2 v) {
    ax = fmaf(u.x, v.x, ax);
    ax = fmaf(-u.y, v.y, ax);
    ay = fmaf(u.x, v.y, ay);
    ay = fmaf(u.y, v.x, ay);
}

// block-diagonal structure of the 36x36 BS gate (total photon number n=0..10)
constexpr int BS_SN[11]  = {1,2,3,4,5,6,5,4,3,2,1};
constexpr int BS_OFF[11] = {0,1,5,14,30,55,91,116,132,141,145};
// mode strides (amp units): {6, 1, 36, 221, 1334}; max addr 7990

// runtime-indexed copy for prep_kernel packing + in-kernel head peel
__device__ const int d_BS_OFF[12] = {0,1,5,14,30,55,91,116,132,141,145,146};
__device__ const int d_BS_SN[11]  = {1,2,3,4,5,6,5,4,3,2,1};

// ---------------------------------------------------------------------------
// Fused prep kernel:
//   blocks 0..79  -> BS gates (order-10 Taylor, s=2 scaling/squaring) packed
//                    block-diag as BROADCAST h2 pairs {ur,ur},{ui,ui}
//   block  80     -> 40 single-mode combined gates (order-10, s=2)
//   blocks 81+    -> dcol: column 0 of expm via vector Horner (order 30, s=0)
// ---------------------------------------------------------------------------
__global__ void prep_kernel(const float* __restrict__ lin,
                            const float* __restrict__ act,
                            const float* __restrict__ lact,
                            const float* __restrict__ x,
                            h2* __restrict__ bsh,
                            h2* __restrict__ sgh,
                            float* __restrict__ dcol,
                            const int total)
{
    __shared__ float2 B0[1296];
    __shared__ float2 B1[1296];
    const int tid = threadIdx.x;

    if (blockIdx.x < 80) {
        const int g = blockIdx.x;
        const int l = g / 20;
        const int w = g % 20;
        const int q = w / 10;
        const int n = w % 10;
        const float theta = lin[l*63 + (q ? 29 : 0) + n];
        const float phi   = lin[l*63 + (q ? 39 : 10) + n];
        const float ts = theta * 0.25f;                 // s=2 scaling
        const float cp = cosf(phi), sp = sinf(phi);
        const float2 u  = make_float2( ts*cp, ts*sp);
        const float2 w2 = make_float2(-ts*cp, ts*sp);

        float2 *R = B0, *T = B1;
        for (int e = tid; e < 1296; e += 256)
            R[e] = make_float2((e % 37 == 0) ? 1.f : 0.f, 0.f);
        __syncthreads();

        for (int k = 10; k >= 1; --k) {
            const float invk = 1.f / (float)k;
            for (int e = tid; e < 1296; e += 256) {
                const int row = e / 36, c = e - row*36;
                const int i = row / 6, j = row - (row/6)*6;
                float ax = 0.f, ay = 0.f;
                if (i < 5 && j > 0) {
                    const float coef = sqrtf((float)((i+1)*j));
                    const float2 xv = R[(row+5)*36 + c];
                    const float px = u.x*xv.x - u.y*xv.y;
                    const float py = u.x*xv.y + u.y*xv.x;
                    ax = fmaf(coef, px, ax); ay = fmaf(coef, py, ay);
                }
                if (i > 0 && j < 5) {
                    const float coef = sqrtf((float)(i*(j+1)));
                    const float2 xv = R[(row-5)*36 + c];
                    const float px = w2.x*xv.x - w2.y*xv.y;
                    const float py = w2.x*xv.y + w2.y*xv.x;
                    ax = fmaf(coef, px, ax); ay = fmaf(coef, py, ay);
                }
                T[e] = make_float2(((row == c) ? 1.f : 0.f) + ax*invk, ay*invk);
            }
            __syncthreads();
            float2* tmp = R; R = T; T = tmp;
        }
        for (int s2 = 0; s2 < 2; ++s2) {                // s=2 squarings
            for (int e = tid; e < 1296; e += 256) {
                const int row = e / 36, c = e - row*36;
                float ax = 0.f, ay = 0.f;
                #pragma unroll 6
                for (int k = 0; k < 36; ++k)
                    cmadd(ax, ay, R[row*36 + k], R[k*36 + c]);
                T[e] = make_float2(ax, ay);
            }
            __syncthreads();
            float2* tmp = R; R = T; T = tmp;
        }
        for (int idx = tid; idx < 146; idx += 256) {
            int nn = 0;
            while (idx >= d_BS_OFF[nn+1]) ++nn;
            const int sn  = d_BS_SN[nn];
            const int rel = idx - d_BS_OFF[nn];
            const int p = rel / sn, qq = rel % sn;
            const int imin = (nn > 5) ? (nn - 5) : 0;
            const int row = 5*(imin + p)  + nn;
            const int col = 5*(imin + qq) + nn;
            const float2 z = R[row*36 + col];
            bsh[g*292 + 2*idx    ] = (h2){(_Float16)z.x, (_Float16)z.x};
            bsh[g*292 + 2*idx + 1] = (h2){(_Float16)z.y, (_Float16)z.y};
        }
    } else if (blockIdx.x == 80) {
        const int t = tid;
        if (t >= 40) return;
        const int l  = t / 10;
        const int gi = t % 10;
        float2 G[36];
        if (gi < 5) {
            // Sq[m] = squeeze(r) @ diag(e^{i rphi1 * n})  (parity-banded)
            const int m = gi;
            const float r    = lin[l*63 + 24 + m];
            const float rphi = (m < 4) ? lin[l*63 + 20 + m] : 0.f;
            float R[36], T[36];
            #pragma unroll
            for (int e = 0; e < 36; ++e) R[e] = (e % 7 == 0) ? 1.f : 0.f;
            float hp[4];
            #pragma unroll
            for (int i = 0; i < 4; ++i)
                hp[i] = 0.5f * r * sqrtf((float)((i+1)*(i+2))) * 0.25f;
            for (int k = 10; k >= 1; --k) {
                const float invk = 1.f / (float)k;
                #pragma unroll
                for (int i = 0; i < 6; ++i) {
                    #pragma unroll
                    for (int c = 0; c < 6; ++c) {
                        float a = 0.f;
                        if (i < 4)  a = fmaf( hp[i],   R[(i+2)*6 + c], a);
                        if (i >= 2) a = fmaf(-hp[i-2], R[(i-2)*6 + c], a);
                        T[i*6+c] = ((i == c) ? 1.f : 0.f) + a*invk;
                    }
                }
                #pragma unroll
                for (int e = 0; e < 36; ++e) R[e] = T[e];
            }
            for (int s2 = 0; s2 < 2; ++s2) {
                #pragma unroll
                for (int i = 0; i < 6; ++i) {
                    #pragma unroll
                    for (int c = 0; c < 6; ++c) {
                        float a = 0.f;
                        #pragma unroll
                        for (int k = 0; k < 6; ++k) a = fmaf(R[i*6+k], R[k*6+c], a);
                        T[i*6+c] = a;
                    }
                }
                #pragma unroll
                for (int e = 0; e < 36; ++e) R[e] = T[e];
            }
            #pragma unroll
            for (int c = 0; c < 6; ++c) {
                const float cc = cosf(rphi * (float)c), ss = sinf(rphi * (float)c);
                #pragma unroll
                for (int o = 0; o < 6; ++o)
                    G[o*6 + c] = make_float2(R[o*6+c]*cc, R[o*6+c]*ss);
            }
        } else {
            // Dp[m] = diag(e^{i kap n^2}) @ disp(dr,dp) @ diag(e^{i rphi2 n})
            const int m = gi - 5;
            const float dr   = lin[l*63 + 53 + m];
            const float dp   = lin[l*63 + 58 + m];
            const float rphi = (m < 4) ? lin[l*63 + 49 + m] : 0.f;
            const float kap  = (l < 3) ? act[l*5 + m] : ((m < 2) ? lact[m] : 0.f);
            const float2 al = make_float2(dr * cosf(dp), dr * sinf(dp));
            float2 R[36], T[36];
            #pragma unroll
            for (int e = 0; e < 36; ++e)
                R[e] = make_float2((e % 7 == 0) ? 1.f : 0.f, 0.f);
            float2 cm[6], cpb[6];
            #pragma unroll
            for (int i = 0; i < 6; ++i) {
                const float sm  = sqrtf((float)i)     * 0.25f;
                const float sp2 = sqrtf((float)(i+1)) * 0.25f;
                cm[i]  = make_float2( al.x*sm,  al.y*sm);
                cpb[i] = make_float2(-al.x*sp2, al.y*sp2);
            }
            for (int k = 10; k >= 1; --k) {
                const float invk = 1.f / (float)k;
                #pragma unroll
                for (int i = 0; i < 6; ++i) {
                    #pragma unroll
                    for (int c = 0; c < 6; ++c) {
                        float ax = 0.f, ay = 0.f;
                        if (i >= 1) cmadd(ax, ay, cm[i],  R[(i-1)*6 + c]);
                        if (i < 5)  cmadd(ax, ay, cpb[i], R[(i+1)*6 + c]);
                        T[i*6+c] = make_float2(((i == c) ? 1.f : 0.f) + ax*invk, ay*invk);
                    }
                }
                #pragma unroll
                for (int e = 0; e < 36; ++e) R[e] = T[e];
            }
            for (int s2 = 0; s2 < 2; ++s2) {
                #pragma unroll
                for (int i = 0; i < 6; ++i) {
                    #pragma unroll
                    for (int c = 0; c < 6; ++c) {
                        float ax = 0.f, ay = 0.f;
                        #pragma unroll
                        for (int k = 0; k < 6; ++k) cmadd(ax, ay, R[i*6+k], R[k*6+c]);
                        T[i*6+c] = make_float2(ax, ay);
                    }
                }
                #pragma unroll
                for (int e = 0; e < 36; ++e) R[e] = T[e];
            }
            #pragma unroll
            for (int o = 0; o < 6; ++o) {
                const float ko = kap * (float)(o*o);
                const float2 kp = make_float2(cosf(ko), sinf(ko));
                #pragma unroll
                for (int c = 0; c < 6; ++c) {
                    const float rc = rphi * (float)c;
                    const float2 rp = make_float2(cosf(rc), sinf(rc));
                    const float2 z = R[o*6 + c];
                    const float2 t1 = make_float2(kp.x*z.x - kp.y*z.y, kp.x*z.y + kp.y*z.x);
                    G[o*6 + c] = make_float2(t1.x*rp.x - t1.y*rp.y, t1.x*rp.y + t1.y*rp.x);
                }
            }
        }
        h2* outp = sgh + (l*10 + gi)*72;
        #pragma unroll
        for (int e = 0; e < 36; ++e) {
            outp[2*e    ] = (h2){(_Float16)G[e].x, (_Float16)G[e].x};
            outp[2*e + 1] = (h2){(_Float16)G[e].y, (_Float16)G[e].y};
        }
    } else {
        // dcol: column 0 of expm(x(A†-A)) via vector Horner, order 30, s=0.
        // (M·w)[i] = x(sqrt(i) w[i-1] - sqrt(i+1) w[i+1]); w = e0 + M w / k.
        const int i = (blockIdx.x - 81) * 256 + tid;
        if (i >= total) return;
        const float xv = x[i];
        float a[5];
        #pragma unroll
        for (int j = 0; j < 5; ++j) a[j] = xv * sqrtf((float)(j+1));
        float w[6];
        #pragma unroll
        for (int j = 0; j < 6; ++j) w[j] = (j == 0) ? 1.f : 0.f;
        for (int k = 30; k >= 1; --k) {
            const float invk = 1.f / (float)k;
            float t[6];
            #pragma unroll
            for (int r = 0; r < 6; ++r) {
                float acc = 0.f;
                if (r >= 1) acc = fmaf( a[r-1], w[r-1], acc);
                if (r < 5)  acc = fmaf(-a[r],   w[r+1], acc);
                t[r] = ((r == 0) ? 1.f : 0.f) + acc*invk;
            }
            #pragma unroll
            for (int j = 0; j < 6; ++j) w[j] = t[j];
        }
        #pragma unroll
        for (int j = 0; j < 6; ++j) dcol[i*6 + j] = w[j];
    }
}

// ---------------------------------------------------------------------------
// Main kernel building blocks (batch-pair packed, 8B complex amplitudes)
// ---------------------------------------------------------------------------

// rows [R0,R1) of photon block n of one BS pass. One ds_read_b64 per input
// amplitude; lo h2 = re{b0,b1}, hi h2 = im{b0,b1}. Broadcast gates:
//   aR += ur*vR - ui*vI ; aI += ur*vI + ui*vR
template<int SA, int SB, int n, int R0, int R1>
__device__ __forceinline__ void bs_rows(const h2* __restrict__ U,
                                        h4* __restrict__ psi,
                                        const int base, const bool act)
{
    constexpr int sn = BS_SN[n], uoff = BS_OFF[n];
    constexpr int imin = (n > 5) ? (n - 5) : 0;
    if (!act) return;
    h2 vR[sn], vI[sn];
    #pragma unroll
    for (int q = 0; q < sn; ++q) {
        const int c = 5*(imin + q) + n;
        const h4 v = psi[base + (c/6)*SA + (c%6)*SB];
        vR[q] = (h2){v.x, v.y};
        vI[q] = (h2){v.z, v.w};
    }
    h2 oR[R1-R0], oI[R1-R0];
    #pragma unroll
    for (int p = R0; p < R1; ++p) {
        const h2* Up = U + 2*(uoff + p*sn);
        h2 ur = Up[0], ui = Up[1];
        h2 aR = ur * vR[0];
        aR = pkfma(-ui, vI[0], aR);
        h2 aI = ur * vI[0];
        aI = pkfma(ui, vR[0], aI);
        #pragma unroll
        for (int q = 1; q < sn; ++q) {
            ur = Up[2*q]; ui = Up[2*q + 1];
            aR = pkfma(ur, vR[q], aR);
            aR = pkfma(-ui, vI[q], aR);
            aI = pkfma(ur, vI[q], aI);
            aI = pkfma(ui, vR[q], aI);
        }
        oR[p-R0] = aR; oI[p-R0] = aI;
    }
    #pragma unroll
    for (int p = R0; p < R1; ++p) {
        const int c = 5*(imin + p) + n;
        const h2 r = oR[p-R0], m = oI[p-R0];
        psi[base + (c/6)*SA + (c%6)*SB] = (h4){r.x, r.y, m.x, m.y};
    }
}

// BS pass: 4 wave-aligned quarters of 256 threads; whole-block groups (no row
// splits -- those race on read-vs-write of shared block inputs).
// packed-cMAC: q0={5}=36, q1={4,2,1}=38, q2={6,8,9}=38, q3={3,7,0,10}=34.
// (max quarter = 38 is optimal for any whole-block partition.)
template<int SA, int SB>
__device__ __forceinline__ void pass_bs(const h2* __restrict__ U,
                                        h4* __restrict__ psi,
                                        const int base, const bool act, const int qid)
{
    if (qid == 0) {
        bs_rows<SA,SB,5,0,6>(U, psi, base, act);
    } else if (qid == 1) {
        bs_rows<SA,SB,4,0,5>(U, psi, base, act);
        bs_rows<SA,SB,2,0,3>(U, psi, base, act);
        bs_rows<SA,SB,1,0,2>(U, psi, base, act);
    } else if (qid == 2) {
        bs_rows<SA,SB,6,0,5>(U, psi, base, act);
        bs_rows<SA,SB,8,0,3>(U, psi, base, act);
        bs_rows<SA,SB,9,0,2>(U, psi, base, act);
    } else {
        bs_rows<SA,SB,3,0,4>(U, psi, base, act);
        bs_rows<SA,SB,7,0,4>(U, psi, base, act);
        bs_rows<SA,SB,0,0,1>(U, psi, base, act);
        bs_rows<SA,SB,10,0,1>(U, psi, base, act);
    }
    __syncthreads();
}

// one single-mode-gate fiber (6 amplitudes, stride SM), 8B-packed
template<int SM, bool SP>
__device__ __forceinline__ void sg_fiber(const h2* __restrict__ G,
                                         h4* __restrict__ psi,
                                         const int base)
{
    h2 vR[6], vI[6];
    #pragma unroll
    for (int k = 0; k < 6; ++k) {
        const h4 v = psi[base + k*SM];
        vR[k] = (h2){v.x, v.y};
        vI[k] = (h2){v.z, v.w};
    }
    h2 oR[6], oI[6];
    #pragma unroll
    for (int o = 0; o < 6; ++o) {
        const int k0 = SP ? (o & 1) : 0;
        const int st = SP ? 2 : 1;
        h2 ur = G[2*(o*6 + k0)], ui = G[2*(o*6 + k0) + 1];
        h2 aR = ur * vR[k0];
        aR = pkfma(-ui, vI[k0], aR);
        h2 aI = ur * vI[k0];
        aI = pkfma(ui, vR[k0], aI);
        #pragma unroll
        for (int k = k0 + st; k < 6; k += st) {
            ur = G[2*(o*6 + k)]; ui = G[2*(o*6 + k) + 1];
            aR = pkfma(ur, vR[k], aR);
            aR = pkfma(-ui, vI[k], aR);
            aI = pkfma(ur, vI[k], aI);
            aI = pkfma(ui, vR[k], aI);
        }
        oR[o] = aR; oI[o] = aI;
    }
    #pragma unroll
    for (int o = 0; o < 6; ++o)
        psi[base + o*SM] = (h4){oR[o].x, oR[o].y, oI[o].x, oI[o].y};
}

// single-mode gate pass: 1296 fibers over 1024 threads (ragged second round).
// dg0/dg1 = precomputed base-6 digits of fiber ids tid and tid+1024.
template<int SM, int S0, int S1, int S2, int S3, bool SP>
__device__ __forceinline__ void pass_sg(const h2* __restrict__ G,
                                        h4* __restrict__ psi,
                                        const int4 dg0, const int4 dg1, const bool act1)
{
    {
        const int base = dg0.x*S0 + dg0.y*S1 + dg0.z*S2 + dg0.w*S3;
        sg_fiber<SM,SP>(G, psi, base);
    }
    if (act1) {
        const int base = dg1.x*S0 + dg1.y*S1 + dg1.z*S2 + dg1.w*S3;
        sg_fiber<SM,SP>(G, psi, base);
    }
    __syncthreads();
}

__global__ __launch_bounds__(1024, 8)
void qnet_kernel(const h2* __restrict__ bs,
                 const h2* __restrict__ sg,
                 const float* __restrict__ dcol,
                 float* __restrict__ out,
                 const int B)
{
    // addr = 6*i0 + i1 + 36*i2 + 221*i3 + 1334*i4 (max 7990), 8B per amplitude
    __shared__ __align__(16) h4 psi[7992];      // 63,936 B
    __shared__ float stf[60];
    __shared__ float red[64];
    // head-peel staging (f32): psi01/psi23 per batch (36), f234 per batch (216)
    __shared__ float2 ps01[2][36];
    __shared__ float2 ps23[2][36];
    __shared__ float2 f234[2][216];

    const int tid = threadIdx.x;
    const int b   = blockIdx.x;          // batch pair (2b, 2b+1)

    const int lim = B * 30;
    if (tid < 60) stf[tid] = (b*60 + tid < lim) ? dcol[b*60 + tid] : 0.f;
    __syncthreads();

    // ---- head peel round A: psi01 = BS01@(d0⊗d1), psi23 = BS23@(d2⊗d3) ----
    // gates: layer0/hf0 pass0 (rail0) at bs+0*292, pass1 (rail2) at bs+1*292
    if (tid < 144) {
        const int part = tid / 36;       // 0:ps01 b0, 1:ps01 b1, 2:ps23 b0, 3:ps23 b1
        const int idx  = tid - part*36;
        const int p    = part & 1;
        const bool m01 = part < 2;
        const int i = idx / 6, j = idx - (idx/6)*6;
        const int n = i + j;
        const int imin = (n > 5) ? (n - 5) : 0;
        const int sn   = d_BS_SN[n];
        const int prow = i - imin;
        const h2* U = bs + (m01 ? 0 : 1)*292 + 2*(d_BS_OFF[n] + prow*sn);
        const float* dA = stf + p*30 + (m01 ? 0 : 12);
        const float* dB = dA + 6;
        float ar = 0.f, ai = 0.f;
        for (int q = 0; q < sn; ++q) {
            const float ur = (float)U[2*q].x, ui = (float)U[2*q+1].x;
            const float dd = dA[imin+q] * dB[n-imin-q];
            ar = fmaf(ur, dd, ar); ai = fmaf(ui, dd, ai);
        }
        if (m01) ps01[p][idx] = make_float2(ar, ai);
        else     ps23[p][idx] = make_float2(ar, ai);
    }
    __syncthreads();

    // ---- head peel round B: f234 = BS34@(psi23⊗d4) (pass3/rail3 commutes
    //      with pass2/rail1, so it legally reorders ahead of it) ----
    if (tid < 432) {
        const int p  = tid / 216;
        const int r  = tid - p*216;
        const int i2 = r / 36, i34 = r - i2*36;
        const int i3 = i34 / 6, i4 = i34 - i3*6;
        const int n  = i3 + i4;
        const int imin = (n > 5) ? (n - 5) : 0;
        const int sn   = d_BS_SN[n];
        const int prow = i3 - imin;
        const h2* U = bs + 3*292 + 2*(d_BS_OFF[n] + prow*sn);
        const float* d4 = stf + p*30 + 24;
        float ar = 0.f, ai = 0.f;
        for (int q = 0; q < sn; ++q) {
            const float ur = (float)U[2*q].x, ui = (float)U[2*q+1].x;
            const float2 w23 = ps23[p][i2*6 + (imin+q)];
            const float dd = d4[n-imin-q];
            ar = fmaf(dd, ur*w23.x - ui*w23.y, ar);
            ai = fmaf(dd, ur*w23.y + ui*w23.x, ai);
        }
        f234[p][r] = make_float2(ar, ai);
    }
    __syncthreads();

    // ---- init: psi = psi01 ⊗ f234 (complex product, rounded once to f16) ----
    for (int e = tid; e < 7776; e += 1024) {
        int t = e;
        const int i4 = t % 6; t /= 6;
        const int i3 = t % 6; t /= 6;
        const int i2 = t % 6; t /= 6;
        const int i1 = t % 6; t /= 6;
        const int i0 = t;
        const int addr = 6*i0 + i1 + 36*i2 + 221*i3 + 1334*i4;
        const int i01 = i0*6 + i1;
        const int r   = i2*36 + i3*6 + i4;
        const float2 a0 = ps01[0][i01], b0 = f234[0][r];
        const float2 a1 = ps01[1][i01], b1 = f234[1][r];
        const float v0r = a0.x*b0.x - a0.y*b0.y, v0i = a0.x*b0.y + a0.y*b0.x;
        const float v1r = a1.x*b1.x - a1.y*b1.y, v1i = a1.x*b1.y + a1.y*b1.x;
        psi[addr] = (h4){(_Float16)v0r, (_Float16)v1r, (_Float16)v0i, (_Float16)v1i};
    }
    __syncthreads();

    // BS mapping: 4 quarters of 256; sub<216 active; fiber f = sub
    const int sub = tid & 255;
    const int qid = __builtin_amdgcn_readfirstlane(tid >> 8);   // wave-uniform
    const bool act = sub < 216;
    const int f = act ? sub : 215;
    const int fa = f / 36, rem = f - fa*36;
    const int fb = rem / 6, fc = rem - fb*6;
    const int baseK0 = fa*36 + fb*221 + fc*1334;   // pair (0,1): spect 2,3,4
    const int baseK1 = fa*6  + fb*221 + fc*1334;   // pair (1,2): spect 0,3,4
    const int baseK2 = rem   + fa*1334;            // pair (2,3): spect 0,1 (contig), 4
    const int baseK3 = f;                          // pair (3,4): spect 0,1,2 (contig)

    // SG mapping: fibers tid and tid+1024 (<1296); digits precomputed once
    int4 dg0, dg1;
    { int t = tid;        dg0.x = t % 6; t /= 6; dg0.y = t % 6; t /= 6; dg0.z = t % 6; dg0.w = t / 6; }
    { int t = tid + 1024; dg1.x = t % 6; t /= 6; dg1.y = t % 6; t /= 6; dg1.z = t % 6; dg1.w = t / 6; }
    const bool act1 = tid < 272;

    for (int l = 0; l < 4; ++l) {
        const h2* bsl = bs + l * 20 * 292;
        const h2* sgl = sg + l * 10 * 72;
        for (int hf = 0; hf < 2; ++hf) {
            const h2* bh = bsl + hf * 10 * 292;
            const h2* sh = sgl + hf * 5 * 72;
            // head peel: first half-layer passes 0,1,3 already applied in init
            const bool first = (l == 0) && (hf == 0);
            // tail skip: in the final half-layer, gates acting only on modes
            // {2,3,4} commute with the X0/X1 measurement -> drop them.
            const bool last = (l == 3) && (hf == 1);
            // rail order k = {0,2,1,3,0,2,1,3,0,2}
            if (!first) {
                pass_bs<6,1>     (bh + 0*292, psi, baseK0, act, qid);
                pass_bs<36,221>  (bh + 1*292, psi, baseK2, act, qid);
            }
            pass_bs<1,36>    (bh + 2*292, psi, baseK1, act, qid);
            if (!first)
                pass_bs<221,1334>(bh + 3*292, psi, baseK3, act, qid);
            pass_bs<6,1>     (bh + 4*292, psi, baseK0, act, qid);
            pass_bs<36,221>  (bh + 5*292, psi, baseK2, act, qid);
            pass_bs<1,36>    (bh + 6*292, psi, baseK1, act, qid);
            if (!last)
                pass_bs<221,1334>(bh + 7*292, psi, baseK3, act, qid);
            pass_bs<6,1>     (bh + 8*292, psi, baseK0, act, qid);
            if (!last)
                pass_bs<36,221>  (bh + 9*292, psi, baseK2, act, qid);
            if (hf == 0) {   // squeeze gates: parity-sparse
                pass_sg<6,    1,36,221,1334, true>(sh + 0*72, psi, dg0, dg1, act1);
                pass_sg<1,    6,36,221,1334, true>(sh + 1*72, psi, dg0, dg1, act1);
                pass_sg<36,   1,6,221,1334,  true>(sh + 2*72, psi, dg0, dg1, act1);
                pass_sg<221,  1,6,36,1334,   true>(sh + 3*72, psi, dg0, dg1, act1);
                pass_sg<1334, 1,6,36,221,    true>(sh + 4*72, psi, dg0, dg1, act1);
            } else {         // displacement gates: dense
                pass_sg<6,    1,36,221,1334, false>(sh + 0*72, psi, dg0, dg1, act1);
                pass_sg<1,    6,36,221,1334, false>(sh + 1*72, psi, dg0, dg1, act1);
                if (!last) {
                    pass_sg<36,   1,6,221,1334,  false>(sh + 2*72, psi, dg0, dg1, act1);
                    pass_sg<221,  1,6,36,1334,   false>(sh + 3*72, psi, dg0, dg1, act1);
                    pass_sg<1334, 1,6,36,221,    false>(sh + 4*72, psi, dg0, dg1, act1);
                }
            }
        }
    }

    // <psi| X psi> on modes 0 (stride 6) and 1 (stride 1); per-batch f32 accum
    float s0a = 0.f, s0b = 0.f, s1a = 0.f, s1b = 0.f;
    for (int fr = tid; fr < 1296; fr += 1024) {
        const int q0 = fr % 6;
        const int q1 = (fr / 6) % 6;
        const int q2 = (fr / 36) % 6;
        const int q3 = fr / 216;
        const int base0 = q0*1 + q1*36 + q2*221 + q3*1334;   // spectators of mode 0
        #pragma unroll
        for (int j = 0; j < 5; ++j) {
            const h4 a = psi[base0 + 6*j];
            const h4 c = psi[base0 + 6*(j+1)];
            const float w = sqrtf((float)(j+1));
            s0a = fmaf(w, fmaf((float)a.z, (float)c.z, (float)a.x*(float)c.x), s0a);
            s0b = fmaf(w, fmaf((float)a.w, (float)c.w, (float)a.y*(float)c.y), s0b);
        }
        const int base1 = q0*6 + q1*36 + q2*221 + q3*1334;   // spectators of mode 1
        #pragma unroll
        for (int j = 0; j < 5; ++j) {
            const h4 a = psi[base1 + j];
            const h4 c = psi[base1 + j + 1];
            const float w = sqrtf((float)(j+1));
            s1a = fmaf(w, fmaf((float)a.z, (float)c.z, (float)a.x*(float)c.x), s1a);
            s1b = fmaf(w, fmaf((float)a.w, (float)c.w, (float)a.y*(float)c.y), s1b);
        }
    }
    #pragma unroll
    for (int off = 32; off > 0; off >>= 1) {
        s0a += __shfl_down(s0a, off, 64);
        s0b += __shfl_down(s0b, off, 64);
        s1a += __shfl_down(s1a, off, 64);
        s1b += __shfl_down(s1b, off, 64);
    }
    if ((tid & 63) == 0) {
        const int w = tid >> 6;
        red[w*4 + 0] = s0a; red[w*4 + 1] = s1a;
        red[w*4 + 2] = s0b; red[w*4 + 3] = s1b;
    }
    __syncthreads();
    if (tid == 0) {
        float r0 = 0.f, r1 = 0.f, r2 = 0.f, r3 = 0.f;
        #pragma unroll
        for (int w = 0; w < 16; ++w) {
            r0 += red[w*4 + 0]; r1 += red[w*4 + 1];
            r2 += red[w*4 + 2]; r3 += red[w*4 + 3];
        }
        const int b0 = 2*b, b1 = 2*b + 1;
        out[b0*2 + 0] = 2.f * r0;
        out[b0*2 + 1] = 2.f * r1;
        if (b1 < B) {
            out[b1*2 + 0] = 2.f * r2;
            out[b1*2 + 1] = 2.f * r3;
        }
    }
}

// ---------------------------------------------------------------------------
extern "C" void kernel_launch(void* const* d_in, const int* in_sizes, int n_in,
                              void* d_out, int out_size, void* d_ws, size_t ws_size,
                              hipStream_t stream)
{
    const float* x    = (const float*)d_in[0];   // (B, 5)
    const float* lin  = (const float*)d_in[1];   // (4, 63)
    const float* act  = (const float*)d_in[2];   // (3, 5)
    const float* lact = (const float*)d_in[3];   // (5,)
    float* out = (float*)d_out;                  // (B, 2) float32

    const int B = in_sizes[0] / 5;

    // ws layout: 80 BS gates (292 h2) | 40 single gates (72 h2) | dcol f32
    h2*    bsh = (h2*)d_ws;
    h2*    sgh = bsh + 80*292;
    float* dc  = (float*)(sgh + 40*72);

    const int total  = B * 5;
    const int nprep  = 81 + (total + 255) / 256;
    prep_kernel<<<dim3(nprep), dim3(256), 0, stream>>>(lin, act, lact, x, bsh, sgh, dc, total);
    qnet_kernel<<<dim3((B + 1) / 2), dim3(1024), 0, stream>>>(bsh, sgh, dc, out, B);
}